// Round 1
// baseline (1018.059 us; speedup 1.0000x reference)
//
#include <hip/hip_runtime.h>

#define F 128            // feature dim (HID == NF == 128)

typedef __attribute__((ext_vector_type(8))) __bf16 bf16x8;
typedef __attribute__((ext_vector_type(4))) float floatx4;

// shifted softplus: softplus(x) - log(2) == log((1+e^x)/2)
__device__ __forceinline__ float ssp(float x) {
    return __logf(fmaf(0.5f, __expf(x), 0.5f));
}

// ---------------------------------------------------------------------------
// prep: convert weights f32 -> bf16 (hi) and residual (lo) where split needed
// ---------------------------------------------------------------------------
__global__ void prep_kernel(const float* __restrict__ fc1w,
                            const float* __restrict__ fw1,
                            const float* __restrict__ fw2,
                            const float* __restrict__ sw1,
                            const float* __restrict__ sw2,
                            __bf16* __restrict__ fc1h, __bf16* __restrict__ fc1l,
                            __bf16* __restrict__ fw1h, __bf16* __restrict__ fw2h,
                            __bf16* __restrict__ sw1h, __bf16* __restrict__ sw1l,
                            __bf16* __restrict__ sw2h, __bf16* __restrict__ sw2l)
{
    int i = blockIdx.x * blockDim.x + threadIdx.x;
    if (i >= F * F) return;
    float v; __bf16 h;
    v = fc1w[i]; h = (__bf16)v; fc1h[i] = h; fc1l[i] = (__bf16)(v - (float)h);
    v = sw1[i];  h = (__bf16)v; sw1h[i] = h; sw1l[i] = (__bf16)(v - (float)h);
    v = sw2[i];  h = (__bf16)v; sw2h[i] = h; sw2l[i] = (__bf16)(v - (float)h);
    fw1h[i] = (__bf16)fw1[i];
    fw2h[i] = (__bf16)fw2[i];
}

// ---------------------------------------------------------------------------
// CSR build: histogram of dst, exclusive scan, cursor scatter -> dst-sorted
// edge order (perm = original edge id per sorted slot, plus sorted src/dst).
// ---------------------------------------------------------------------------
__global__ __launch_bounds__(256) void hist_kernel(const int* __restrict__ eidx,
                                                   int* __restrict__ cnt, int E)
{
    int i = blockIdx.x * 256 + threadIdx.x;
    if (i < E) atomicAdd(&cnt[eidx[E + i]], 1);
}

// in-place block-level exclusive scan (1024 elems/block) + block totals
__global__ __launch_bounds__(1024) void scan1_kernel(int* __restrict__ cnt,
                                                     int* __restrict__ bsums, int N)
{
    __shared__ int sd[1024];
    const int t = threadIdx.x;
    const int i = blockIdx.x * 1024 + t;
    int v = (i < N) ? cnt[i] : 0;
    sd[t] = v;
    __syncthreads();
    for (int off = 1; off < 1024; off <<= 1) {
        int add = (t >= off) ? sd[t - off] : 0;
        __syncthreads();
        sd[t] += add;
        __syncthreads();
    }
    if (i < N) cnt[i] = sd[t] - v;          // exclusive
    if (t == 1023) bsums[blockIdx.x] = sd[t];
}

__global__ void scan2_kernel(int* __restrict__ bsums, int nb)
{
    if (threadIdx.x == 0 && blockIdx.x == 0) {
        int acc = 0;
        for (int j = 0; j < nb; ++j) { int c = bsums[j]; bsums[j] = acc; acc += c; }
    }
}

__global__ __launch_bounds__(1024) void scan3_kernel(int* __restrict__ cnt,
                                                     const int* __restrict__ bsums, int N)
{
    int i = blockIdx.x * 1024 + threadIdx.x;
    if (i < N) cnt[i] += bsums[blockIdx.x];
}

__global__ __launch_bounds__(256) void scatter_kernel(const int* __restrict__ eidx,
                                                      int* __restrict__ cursor,
                                                      int* __restrict__ perm,
                                                      int* __restrict__ ssrc,
                                                      int* __restrict__ sdst, int E)
{
    int i = blockIdx.x * 256 + threadIdx.x;
    if (i < E) {
        int d = eidx[E + i];
        int slot = atomicAdd(&cursor[d], 1);
        perm[slot] = i;
        ssrc[slot] = eidx[i];
        sdst[slot] = d;
    }
}

// ---------------------------------------------------------------------------
// y = x @ fc1_w.T   (split bf16, 3-term MFMA -> ~f32 exact)
// ---------------------------------------------------------------------------
__global__ __launch_bounds__(256) void fc1_kernel(
    const float* __restrict__ x, const __bf16* __restrict__ wh,
    const __bf16* __restrict__ wl, float* __restrict__ y, int M)
{
    const int tid = threadIdx.x;
    const int wv = tid >> 6, lane = tid & 63;
    const int m16 = lane & 15, q = lane >> 4;
    const int g = wv & 1, c = wv >> 1;
    const int rowA0 = blockIdx.x * 32 + g * 16 + m16;
    const int rowA = rowA0 < M ? rowA0 : M - 1;

    floatx4 acc[4] = {};
    #pragma unroll
    for (int ks = 0; ks < 4; ++ks) {
        const int kb = ks * 32 + q * 8;
        const float4* p = (const float4*)(x + (size_t)rowA * F + kb);
        float4 a0 = p[0], a1 = p[1];
        float fv[8] = {a0.x, a0.y, a0.z, a0.w, a1.x, a1.y, a1.z, a1.w};
        bf16x8 ah, al;
        #pragma unroll
        for (int i = 0; i < 8; ++i) {
            __bf16 h = (__bf16)fv[i];
            ah[i] = h; al[i] = (__bf16)(fv[i] - (float)h);
        }
        #pragma unroll
        for (int nt = 0; nt < 4; ++nt) {
            const size_t wo = (size_t)(c * 64 + nt * 16 + m16) * F + kb;
            bf16x8 bh = *(const bf16x8*)(wh + wo);
            bf16x8 bl = *(const bf16x8*)(wl + wo);
            acc[nt] = __builtin_amdgcn_mfma_f32_16x16x32_bf16(ah, bh, acc[nt], 0, 0, 0);
            acc[nt] = __builtin_amdgcn_mfma_f32_16x16x32_bf16(al, bh, acc[nt], 0, 0, 0);
            acc[nt] = __builtin_amdgcn_mfma_f32_16x16x32_bf16(ah, bl, acc[nt], 0, 0, 0);
        }
    }
    const int rowD0 = blockIdx.x * 32 + g * 16 + q * 4;
    #pragma unroll
    for (int nt = 0; nt < 4; ++nt) {
        const int col = c * 64 + nt * 16 + m16;
        #pragma unroll
        for (int r = 0; r < 4; ++r) {
            const int row = rowD0 + r;
            if (row < M) y[(size_t)row * F + col] = acc[nt][r];
        }
    }
}

// ---------------------------------------------------------------------------
// Edge kernel over dst-SORTED slots: W = ssp(ssp(ea@f_w1.T+b1)@f_w2.T+b2);
// msg = y[src]*W; in-register merge of equal-dst runs, then atomic scatter.
// block = 256 thr, 64 sorted edges/block.
// ---------------------------------------------------------------------------
__global__ __launch_bounds__(256) void edge_kernel(
    const float* __restrict__ edge_attr,
    const int* __restrict__ perm,
    const int* __restrict__ ssrc,
    const int* __restrict__ sdst,
    const float* __restrict__ fb1, const float* __restrict__ fb2,
    const __bf16* __restrict__ fw1, const __bf16* __restrict__ fw2,
    const float* __restrict__ y,
    float* __restrict__ agg, int E)
{
    __shared__ __bf16 h1[64][136];   // stride 136 dwords%32 -> conflict-free b128

    const int tid = threadIdx.x;
    const int wv = tid >> 6, lane = tid & 63;
    const int m16 = lane & 15, q = lane >> 4;
    const int e0 = blockIdx.x * 64;
    const int pA0 = e0 + wv * 16 + m16;
    const int pA = pA0 < E ? pA0 : E - 1;
    const int eA = perm[pA];                 // original edge id for this row

    // ---- stage 1: h1 = ssp(ea @ f_w1.T + b1) ----
    floatx4 acc[8] = {};
    #pragma unroll
    for (int ks = 0; ks < 4; ++ks) {
        const int kb = ks * 32 + q * 8;
        const float4* pa = (const float4*)(edge_attr + (size_t)eA * F + kb);
        float4 a0 = pa[0], a1 = pa[1];
        float fv[8] = {a0.x, a0.y, a0.z, a0.w, a1.x, a1.y, a1.z, a1.w};
        bf16x8 aF;
        #pragma unroll
        for (int i = 0; i < 8; ++i) aF[i] = (__bf16)fv[i];
        #pragma unroll
        for (int nt = 0; nt < 8; ++nt) {
            bf16x8 bF = *(const bf16x8*)(fw1 + (size_t)(nt * 16 + m16) * F + kb);
            acc[nt] = __builtin_amdgcn_mfma_f32_16x16x32_bf16(aF, bF, acc[nt], 0, 0, 0);
        }
    }
    #pragma unroll
    for (int nt = 0; nt < 8; ++nt) {
        const int col = nt * 16 + m16;
        const float b = fb1[col];
        #pragma unroll
        for (int r = 0; r < 4; ++r) {
            const int row = wv * 16 + q * 4 + r;
            h1[row][col] = (__bf16)ssp(acc[nt][r] + b);
        }
    }
    __syncthreads();

    // ---- stage 2: W = ssp(h1 @ f_w2.T + b2) ----
    floatx4 zero = {};
    #pragma unroll
    for (int nt = 0; nt < 8; ++nt) acc[nt] = zero;
    #pragma unroll
    for (int ks = 0; ks < 4; ++ks) {
        const int kb = ks * 32 + q * 8;
        bf16x8 aF = *(const bf16x8*)(&h1[wv * 16 + m16][kb]);
        #pragma unroll
        for (int nt = 0; nt < 8; ++nt) {
            bf16x8 bF = *(const bf16x8*)(fw2 + (size_t)(nt * 16 + m16) * F + kb);
            acc[nt] = __builtin_amdgcn_mfma_f32_16x16x32_bf16(aF, bF, acc[nt], 0, 0, 0);
        }
    }

    // ---- stage 3: msg = y[src] * W, run-merged atomic scatter to agg[dst] ----
    int src[4], dst[4], ok[4];
    #pragma unroll
    for (int r = 0; r < 4; ++r) {
        const int p = e0 + wv * 16 + q * 4 + r;
        const int pc = p < E ? p : E - 1;
        ok[r] = (p < E);
        src[r] = ssrc[pc];
        dst[r] = sdst[pc];
    }
    #pragma unroll
    for (int nt = 0; nt < 8; ++nt) {
        const int col = nt * 16 + m16;
        const float b = fb2[col];
        float run = 0.f;
        #pragma unroll
        for (int r = 0; r < 4; ++r) {
            if (ok[r]) {
                const float wV = ssp(acc[nt][r] + b);
                run += y[(size_t)src[r] * F + col] * wV;
                const bool flush = (r == 3) || (!ok[r + 1]) || (dst[r + 1] != dst[r]);
                if (flush) {
                    unsafeAtomicAdd(&agg[(size_t)dst[r] * F + col], run);
                    run = 0.f;
                }
            }
        }
    }
}

// ---------------------------------------------------------------------------
// out = ssp(agg @ s_w1.T) @ s_w2.T   (split bf16 both stages -> ~f32 exact)
// ---------------------------------------------------------------------------
__global__ __launch_bounds__(256) void state_kernel(
    const float* __restrict__ agg,
    const __bf16* __restrict__ w1h, const __bf16* __restrict__ w1l,
    const __bf16* __restrict__ w2h, const __bf16* __restrict__ w2l,
    float* __restrict__ out, int M)
{
    __shared__ __bf16 hh[32][136];
    __shared__ __bf16 hl[32][136];

    const int tid = threadIdx.x;
    const int wv = tid >> 6, lane = tid & 63;
    const int m16 = lane & 15, q = lane >> 4;
    const int g = wv & 1, c = wv >> 1;
    const int rowA0 = blockIdx.x * 32 + g * 16 + m16;
    const int rowA = rowA0 < M ? rowA0 : M - 1;

    floatx4 acc[4] = {};
    #pragma unroll
    for (int ks = 0; ks < 4; ++ks) {
        const int kb = ks * 32 + q * 8;
        const float4* p = (const float4*)(agg + (size_t)rowA * F + kb);
        float4 a0 = p[0], a1 = p[1];
        float fv[8] = {a0.x, a0.y, a0.z, a0.w, a1.x, a1.y, a1.z, a1.w};
        bf16x8 ah, al;
        #pragma unroll
        for (int i = 0; i < 8; ++i) {
            __bf16 h = (__bf16)fv[i];
            ah[i] = h; al[i] = (__bf16)(fv[i] - (float)h);
        }
        #pragma unroll
        for (int nt = 0; nt < 4; ++nt) {
            const size_t wo = (size_t)(c * 64 + nt * 16 + m16) * F + kb;
            bf16x8 bh = *(const bf16x8*)(w1h + wo);
            bf16x8 bl = *(const bf16x8*)(w1l + wo);
            acc[nt] = __builtin_amdgcn_mfma_f32_16x16x32_bf16(ah, bh, acc[nt], 0, 0, 0);
            acc[nt] = __builtin_amdgcn_mfma_f32_16x16x32_bf16(al, bh, acc[nt], 0, 0, 0);
            acc[nt] = __builtin_amdgcn_mfma_f32_16x16x32_bf16(ah, bl, acc[nt], 0, 0, 0);
        }
    }
    #pragma unroll
    for (int nt = 0; nt < 4; ++nt) {
        const int col = c * 64 + nt * 16 + m16;
        #pragma unroll
        for (int r = 0; r < 4; ++r) {
            const int row = g * 16 + q * 4 + r;
            const float h = ssp(acc[nt][r]);
            const __bf16 H = (__bf16)h;
            hh[row][col] = H;
            hl[row][col] = (__bf16)(h - (float)H);
        }
    }
    __syncthreads();

    floatx4 zero = {};
    #pragma unroll
    for (int nt = 0; nt < 4; ++nt) acc[nt] = zero;
    #pragma unroll
    for (int ks = 0; ks < 4; ++ks) {
        const int kb = ks * 32 + q * 8;
        bf16x8 aH = *(const bf16x8*)(&hh[g * 16 + m16][kb]);
        bf16x8 aL = *(const bf16x8*)(&hl[g * 16 + m16][kb]);
        #pragma unroll
        for (int nt = 0; nt < 4; ++nt) {
            const size_t wo = (size_t)(c * 64 + nt * 16 + m16) * F + kb;
            bf16x8 bh = *(const bf16x8*)(w2h + wo);
            bf16x8 bl = *(const bf16x8*)(w2l + wo);
            acc[nt] = __builtin_amdgcn_mfma_f32_16x16x32_bf16(aH, bh, acc[nt], 0, 0, 0);
            acc[nt] = __builtin_amdgcn_mfma_f32_16x16x32_bf16(aL, bh, acc[nt], 0, 0, 0);
            acc[nt] = __builtin_amdgcn_mfma_f32_16x16x32_bf16(aH, bl, acc[nt], 0, 0, 0);
        }
    }
    const int rowD0 = blockIdx.x * 32 + g * 16 + q * 4;
    #pragma unroll
    for (int nt = 0; nt < 4; ++nt) {
        const int col = c * 64 + nt * 16 + m16;
        #pragma unroll
        for (int r = 0; r < 4; ++r) {
            const int row = rowD0 + r;
            if (row < M) out[(size_t)row * F + col] = acc[nt][r];
        }
    }
}

// ---------------------------------------------------------------------------
extern "C" void kernel_launch(void* const* d_in, const int* in_sizes, int n_in,
                              void* d_out, int out_size, void* d_ws, size_t ws_size,
                              hipStream_t stream)
{
    const float* x         = (const float*)d_in[0];
    const float* edge_attr = (const float*)d_in[1];
    const int*   eidx      = (const int*)d_in[2];
    const float* fc1w      = (const float*)d_in[3];
    const float* fw1       = (const float*)d_in[4];
    const float* fb1       = (const float*)d_in[5];
    const float* fw2       = (const float*)d_in[6];
    const float* fb2       = (const float*)d_in[7];
    const float* sw1       = (const float*)d_in[8];
    const float* sw2       = (const float*)d_in[9];
    float* out = (float*)d_out;

    const int N = in_sizes[0] / F;     // 50000
    const int E = in_sizes[1] / F;     // 600000

    float* agg = (float*)d_ws;
    float* y   = agg + (size_t)N * F;
    __bf16* wb = (__bf16*)(y + (size_t)N * F);
    const int WSZ = F * F;
    __bf16* fc1h = wb;            __bf16* fc1l = wb + WSZ;
    __bf16* fw1h = wb + 2 * WSZ;  __bf16* fw2h = wb + 3 * WSZ;
    __bf16* sw1h = wb + 4 * WSZ;  __bf16* sw1l = wb + 5 * WSZ;
    __bf16* sw2h = wb + 6 * WSZ;  __bf16* sw2l = wb + 7 * WSZ;
    int* cnt   = (int*)(wb + 8 * WSZ);       // N counters -> exclusive scan -> cursor
    int* bsums = cnt + N;                    // 64 block sums (49 used)
    int* perm  = bsums + 64;                 // E: original edge id per sorted slot
    int* ssrc  = perm + E;                   // E: src per sorted slot
    int* sdst  = ssrc + E;                   // E: dst per sorted slot (ascending)

    const int nb1 = (N + 1023) / 1024;       // 49 scan blocks

    // agg must start at zero (ws is poisoned before every launch)
    hipMemsetAsync(agg, 0, (size_t)N * F * sizeof(float), stream);
    hipMemsetAsync(cnt, 0, (size_t)N * sizeof(int), stream);

    prep_kernel<<<(WSZ + 255) / 256, 256, 0, stream>>>(
        fc1w, fw1, fw2, sw1, sw2, fc1h, fc1l, fw1h, fw2h, sw1h, sw1l, sw2h, sw2l);

    fc1_kernel<<<(N + 31) / 32, 256, 0, stream>>>(x, fc1h, fc1l, y, N);

    // build dst-sorted edge order
    hist_kernel<<<(E + 255) / 256, 256, 0, stream>>>(eidx, cnt, E);
    scan1_kernel<<<nb1, 1024, 0, stream>>>(cnt, bsums, N);
    scan2_kernel<<<1, 64, 0, stream>>>(bsums, nb1);
    scan3_kernel<<<nb1, 1024, 0, stream>>>(cnt, bsums, N);
    scatter_kernel<<<(E + 255) / 256, 256, 0, stream>>>(eidx, cnt, perm, ssrc, sdst, E);

    edge_kernel<<<(E + 63) / 64, 256, 0, stream>>>(
        edge_attr, perm, ssrc, sdst, fb1, fb2, fw1h, fw2h, y, agg, E);

    state_kernel<<<(N + 31) / 32, 256, 0, stream>>>(
        agg, sw1h, sw1l, sw2h, sw2l, out, N);
}

// Round 2
// 966.415 us; speedup vs baseline: 1.0534x; 1.0534x over previous
//
#include <hip/hip_runtime.h>

#define F 128            // feature dim (HID == NF == 128)
#define SP 16            // sorted slots per wave in agg_kernel

typedef __attribute__((ext_vector_type(8))) __bf16 bf16x8;
typedef __attribute__((ext_vector_type(4))) float floatx4;
typedef __attribute__((ext_vector_type(2))) _Float16 f16x2;

// shifted softplus: softplus(x) - log(2) == log((1+e^x)/2)
__device__ __forceinline__ float ssp(float x) {
    return __logf(fmaf(0.5f, __expf(x), 0.5f));
}

// ---------------------------------------------------------------------------
// prep: weights f32 -> bf16(hi)+bf16(lo); also zero the histogram counters
// ---------------------------------------------------------------------------
__global__ void prep_kernel(const float* __restrict__ fc1w,
                            const float* __restrict__ fw1,
                            const float* __restrict__ fw2,
                            const float* __restrict__ sw1,
                            const float* __restrict__ sw2,
                            __bf16* __restrict__ fc1h, __bf16* __restrict__ fc1l,
                            __bf16* __restrict__ fw1h, __bf16* __restrict__ fw2h,
                            __bf16* __restrict__ sw1h, __bf16* __restrict__ sw1l,
                            __bf16* __restrict__ sw2h, __bf16* __restrict__ sw2l,
                            int* __restrict__ cnt, int N)
{
    int i = blockIdx.x * blockDim.x + threadIdx.x;
    for (int j = i; j < N; j += gridDim.x * blockDim.x) cnt[j] = 0;
    if (i >= F * F) return;
    float v; __bf16 h;
    v = fc1w[i]; h = (__bf16)v; fc1h[i] = h; fc1l[i] = (__bf16)(v - (float)h);
    v = sw1[i];  h = (__bf16)v; sw1h[i] = h; sw1l[i] = (__bf16)(v - (float)h);
    v = sw2[i];  h = (__bf16)v; sw2h[i] = h; sw2l[i] = (__bf16)(v - (float)h);
    fw1h[i] = (__bf16)fw1[i];
    fw2h[i] = (__bf16)fw2[i];
}

// ---------------------------------------------------------------------------
// CSR build: histogram of dst -> exclusive scan -> cursor scatter.
// After scatter_kernel, cnt[n] == end offset of node n's slot range.
// pos[e] = sorted slot of original edge e (inverse permutation).
// ---------------------------------------------------------------------------
__global__ __launch_bounds__(256) void hist_kernel(const int* __restrict__ eidx,
                                                   int* __restrict__ cnt, int E)
{
    int i = blockIdx.x * 256 + threadIdx.x;
    if (i < E) atomicAdd(&cnt[eidx[E + i]], 1);
}

__global__ __launch_bounds__(1024) void scan1_kernel(int* __restrict__ cnt,
                                                     int* __restrict__ bsums, int N)
{
    __shared__ int sd[1024];
    const int t = threadIdx.x;
    const int i = blockIdx.x * 1024 + t;
    int v = (i < N) ? cnt[i] : 0;
    sd[t] = v;
    __syncthreads();
    for (int off = 1; off < 1024; off <<= 1) {
        int add = (t >= off) ? sd[t - off] : 0;
        __syncthreads();
        sd[t] += add;
        __syncthreads();
    }
    if (i < N) cnt[i] = sd[t] - v;          // exclusive
    if (t == 1023) bsums[blockIdx.x] = sd[t];
}

// one-wave shuffle exclusive scan over <=64 block sums (was single-thread serial)
__global__ void scan2_kernel(int* __restrict__ bsums, int nb)
{
    const int lane = threadIdx.x & 63;
    int v = (lane < nb) ? bsums[lane] : 0;
    int acc = v;
    #pragma unroll
    for (int off = 1; off < 64; off <<= 1) {
        int t = __shfl_up(acc, off);
        if (lane >= off) acc += t;
    }
    if (lane < nb) bsums[lane] = acc - v;   // exclusive
}

__global__ __launch_bounds__(1024) void scan3_kernel(int* __restrict__ cnt,
                                                     const int* __restrict__ bsums, int N)
{
    int i = blockIdx.x * 1024 + threadIdx.x;
    if (i < N) cnt[i] += bsums[blockIdx.x];
}

__global__ __launch_bounds__(256) void scatter_kernel(const int* __restrict__ eidx,
                                                      int* __restrict__ cursor,
                                                      int* __restrict__ pos,
                                                      int* __restrict__ ssrc,
                                                      int* __restrict__ sdst, int E)
{
    int i = blockIdx.x * 256 + threadIdx.x;
    if (i < E) {
        int d = eidx[E + i];
        int slot = atomicAdd(&cursor[d], 1);
        pos[i] = slot;
        ssrc[slot] = eidx[i];
        sdst[slot] = d;
    }
}

// ---------------------------------------------------------------------------
// y = x @ fc1_w.T   (split bf16, 3-term MFMA -> ~f32 exact)
// ---------------------------------------------------------------------------
__global__ __launch_bounds__(256) void fc1_kernel(
    const float* __restrict__ x, const __bf16* __restrict__ wh,
    const __bf16* __restrict__ wl, float* __restrict__ y, int M)
{
    const int tid = threadIdx.x;
    const int wv = tid >> 6, lane = tid & 63;
    const int m16 = lane & 15, q = lane >> 4;
    const int g = wv & 1, c = wv >> 1;
    const int rowA0 = blockIdx.x * 32 + g * 16 + m16;
    const int rowA = rowA0 < M ? rowA0 : M - 1;

    floatx4 acc[4] = {};
    #pragma unroll
    for (int ks = 0; ks < 4; ++ks) {
        const int kb = ks * 32 + q * 8;
        const float4* p = (const float4*)(x + (size_t)rowA * F + kb);
        float4 a0 = p[0], a1 = p[1];
        float fv[8] = {a0.x, a0.y, a0.z, a0.w, a1.x, a1.y, a1.z, a1.w};
        bf16x8 ah, al;
        #pragma unroll
        for (int i = 0; i < 8; ++i) {
            __bf16 h = (__bf16)fv[i];
            ah[i] = h; al[i] = (__bf16)(fv[i] - (float)h);
        }
        #pragma unroll
        for (int nt = 0; nt < 4; ++nt) {
            const size_t wo = (size_t)(c * 64 + nt * 16 + m16) * F + kb;
            bf16x8 bh = *(const bf16x8*)(wh + wo);
            bf16x8 bl = *(const bf16x8*)(wl + wo);
            acc[nt] = __builtin_amdgcn_mfma_f32_16x16x32_bf16(ah, bh, acc[nt], 0, 0, 0);
            acc[nt] = __builtin_amdgcn_mfma_f32_16x16x32_bf16(al, bh, acc[nt], 0, 0, 0);
            acc[nt] = __builtin_amdgcn_mfma_f32_16x16x32_bf16(ah, bl, acc[nt], 0, 0, 0);
        }
    }
    const int rowD0 = blockIdx.x * 32 + g * 16 + q * 4;
    #pragma unroll
    for (int nt = 0; nt < 4; ++nt) {
        const int col = c * 64 + nt * 16 + m16;
        #pragma unroll
        for (int r = 0; r < 4; ++r) {
            const int row = rowD0 + r;
            if (row < M) y[(size_t)row * F + col] = acc[nt][r];
        }
    }
}

// ---------------------------------------------------------------------------
// Pass E1: W = ssp(ssp(ea@f_w1.T+b1)@f_w2.T+b2) for edges in ORIGINAL order
// (pure streaming reads), stored as fp16 rows at dst-sorted slot pos[e]
// (scattered writes are fire-and-forget). LDS buffer reused bf16->fp16.
// ---------------------------------------------------------------------------
__global__ __launch_bounds__(256) void filter_kernel(
    const float* __restrict__ edge_attr,
    const int* __restrict__ pos,
    const float* __restrict__ fb1, const float* __restrict__ fb2,
    const __bf16* __restrict__ fw1, const __bf16* __restrict__ fw2,
    _Float16* __restrict__ Ws, int E)
{
    __shared__ __align__(16) unsigned short smem[64][136]; // bf16 h1, then fp16 W
    __shared__ int pos_s[64];
    __bf16 (*h1)[136] = (__bf16 (*)[136])smem;
    _Float16 (*wo)[136] = (_Float16 (*)[136])smem;

    const int tid = threadIdx.x;
    const int wv = tid >> 6, lane = tid & 63;
    const int m16 = lane & 15, q = lane >> 4;
    const int e0 = blockIdx.x * 64;
    if (tid < 64) { int e = e0 + tid; pos_s[tid] = pos[e < E ? e : E - 1]; }
    const int rowA0 = e0 + wv * 16 + m16;
    const int rowA = rowA0 < E ? rowA0 : E - 1;

    // ---- stage 1: h1 = ssp(ea @ f_w1.T + b1) ----
    floatx4 acc[8] = {};
    #pragma unroll
    for (int ks = 0; ks < 4; ++ks) {
        const int kb = ks * 32 + q * 8;
        const float4* pa = (const float4*)(edge_attr + (size_t)rowA * F + kb);
        float4 a0 = pa[0], a1 = pa[1];
        float fv[8] = {a0.x, a0.y, a0.z, a0.w, a1.x, a1.y, a1.z, a1.w};
        bf16x8 aF;
        #pragma unroll
        for (int i = 0; i < 8; ++i) aF[i] = (__bf16)fv[i];
        #pragma unroll
        for (int nt = 0; nt < 8; ++nt) {
            bf16x8 bF = *(const bf16x8*)(fw1 + (size_t)(nt * 16 + m16) * F + kb);
            acc[nt] = __builtin_amdgcn_mfma_f32_16x16x32_bf16(aF, bF, acc[nt], 0, 0, 0);
        }
    }
    #pragma unroll
    for (int nt = 0; nt < 8; ++nt) {
        const int col = nt * 16 + m16;
        const float b = fb1[col];
        #pragma unroll
        for (int r = 0; r < 4; ++r) {
            const int row = wv * 16 + q * 4 + r;
            h1[row][col] = (__bf16)ssp(acc[nt][r] + b);
        }
    }
    __syncthreads();

    // ---- stage 2: W = ssp(h1 @ f_w2.T + b2) ----
    floatx4 zero = {};
    #pragma unroll
    for (int nt = 0; nt < 8; ++nt) acc[nt] = zero;
    #pragma unroll
    for (int ks = 0; ks < 4; ++ks) {
        const int kb = ks * 32 + q * 8;
        bf16x8 aF = *(const bf16x8*)(&h1[wv * 16 + m16][kb]);
        #pragma unroll
        for (int nt = 0; nt < 8; ++nt) {
            bf16x8 bF = *(const bf16x8*)(fw2 + (size_t)(nt * 16 + m16) * F + kb);
            acc[nt] = __builtin_amdgcn_mfma_f32_16x16x32_bf16(aF, bF, acc[nt], 0, 0, 0);
        }
    }
    __syncthreads();   // all h1 reads done; smem can be retyped to fp16 W

    #pragma unroll
    for (int nt = 0; nt < 8; ++nt) {
        const int col = nt * 16 + m16;
        const float b = fb2[col];
        #pragma unroll
        for (int r = 0; r < 4; ++r) {
            const int row = wv * 16 + q * 4 + r;
            wo[row][col] = (_Float16)ssp(acc[nt][r] + b);
        }
    }
    __syncthreads();

    // coalesced scatter: each row is 256B contiguous at slot pos_s[row]
    #pragma unroll
    for (int r2 = 0; r2 < 4; ++r2) {
        const int row = wv * 16 + r2 * 4 + q;
        const int e = e0 + row;
        if (e < E) {
            const uint4 v = *(const uint4*)(&wo[row][m16 * 8]);
            *(uint4*)(Ws + (size_t)pos_s[row] * F + m16 * 8) = v;
        }
    }
}

// ---------------------------------------------------------------------------
// Pass E2: agg[dst] += y[src] * W  over dst-SORTED slots.
// Wave owns SP consecutive slots, lane owns 2 columns. W reads sequential,
// y rows fully coalesced (L3-resident). Loads batched 4 slots deep; runs of
// equal dst merged in registers before the atomic flush.
// ---------------------------------------------------------------------------
__global__ __launch_bounds__(256) void agg_kernel(
    const float* __restrict__ y, const _Float16* __restrict__ Ws,
    const int* __restrict__ ssrc, const int* __restrict__ sdst,
    float* __restrict__ agg, int E)
{
    const int tid = threadIdx.x;
    const int wv = tid >> 6, lane = tid & 63;
    const long s0 = ((long)blockIdx.x * 4 + wv) * SP;
    if (s0 >= E) return;

    int msrc = 0, mdst = -1;
    if (lane < SP) {
        long s = s0 + lane;
        if (s < E) { msrc = ssrc[s]; mdst = sdst[s]; }
    }
    const int col = lane * 2;
    float rx = 0.f, ry = 0.f;
    int rdst = -1;

    #pragma unroll
    for (int c = 0; c < SP / 4; ++c) {
        float2 yv[4]; float wx[4], wy[4]; int pdst[4]; bool okr[4];
        #pragma unroll
        for (int r = 0; r < 4; ++r) {
            const int p = c * 4 + r;
            const long s = s0 + p;
            okr[r] = (s < E);
            const int sp = __shfl(msrc, p);
            pdst[r] = __shfl(mdst, p);
            const long sc = okr[r] ? s : (long)(E - 1);
            const int spc = okr[r] ? sp : 0;
            yv[r] = *(const float2*)(y + (size_t)spc * F + col);
            f16x2 w2 = *(const f16x2*)(Ws + (size_t)sc * F + col);
            wx[r] = (float)w2[0]; wy[r] = (float)w2[1];
        }
        #pragma unroll
        for (int r = 0; r < 4; ++r) {
            if (!okr[r]) continue;
            if (pdst[r] != rdst) {
                if (rdst >= 0) {
                    unsafeAtomicAdd(&agg[(size_t)rdst * F + col], rx);
                    unsafeAtomicAdd(&agg[(size_t)rdst * F + col + 1], ry);
                }
                rx = 0.f; ry = 0.f; rdst = pdst[r];
            }
            rx = fmaf(yv[r].x, wx[r], rx);
            ry = fmaf(yv[r].y, wy[r], ry);
        }
    }
    if (rdst >= 0) {
        unsafeAtomicAdd(&agg[(size_t)rdst * F + col], rx);
        unsafeAtomicAdd(&agg[(size_t)rdst * F + col + 1], ry);
    }
}

// ---------------------------------------------------------------------------
// out = ssp(agg @ s_w1.T) @ s_w2.T   (split bf16 both stages -> ~f32 exact)
// ---------------------------------------------------------------------------
__global__ __launch_bounds__(256) void state_kernel(
    const float* __restrict__ agg,
    const __bf16* __restrict__ w1h, const __bf16* __restrict__ w1l,
    const __bf16* __restrict__ w2h, const __bf16* __restrict__ w2l,
    float* __restrict__ out, int M)
{
    __shared__ __bf16 hh[32][136];
    __shared__ __bf16 hl[32][136];

    const int tid = threadIdx.x;
    const int wv = tid >> 6, lane = tid & 63;
    const int m16 = lane & 15, q = lane >> 4;
    const int g = wv & 1, c = wv >> 1;
    const int rowA0 = blockIdx.x * 32 + g * 16 + m16;
    const int rowA = rowA0 < M ? rowA0 : M - 1;

    floatx4 acc[4] = {};
    #pragma unroll
    for (int ks = 0; ks < 4; ++ks) {
        const int kb = ks * 32 + q * 8;
        const float4* p = (const float4*)(agg + (size_t)rowA * F + kb);
        float4 a0 = p[0], a1 = p[1];
        float fv[8] = {a0.x, a0.y, a0.z, a0.w, a1.x, a1.y, a1.z, a1.w};
        bf16x8 ah, al;
        #pragma unroll
        for (int i = 0; i < 8; ++i) {
            __bf16 h = (__bf16)fv[i];
            ah[i] = h; al[i] = (__bf16)(fv[i] - (float)h);
        }
        #pragma unroll
        for (int nt = 0; nt < 4; ++nt) {
            const size_t wo = (size_t)(c * 64 + nt * 16 + m16) * F + kb;
            bf16x8 bh = *(const bf16x8*)(w1h + wo);
            bf16x8 bl = *(const bf16x8*)(w1l + wo);
            acc[nt] = __builtin_amdgcn_mfma_f32_16x16x32_bf16(ah, bh, acc[nt], 0, 0, 0);
            acc[nt] = __builtin_amdgcn_mfma_f32_16x16x32_bf16(al, bh, acc[nt], 0, 0, 0);
            acc[nt] = __builtin_amdgcn_mfma_f32_16x16x32_bf16(ah, bl, acc[nt], 0, 0, 0);
        }
    }
    #pragma unroll
    for (int nt = 0; nt < 4; ++nt) {
        const int col = c * 64 + nt * 16 + m16;
        #pragma unroll
        for (int r = 0; r < 4; ++r) {
            const int row = g * 16 + q * 4 + r;
            const float h = ssp(acc[nt][r]);
            const __bf16 H = (__bf16)h;
            hh[row][col] = H;
            hl[row][col] = (__bf16)(h - (float)H);
        }
    }
    __syncthreads();

    floatx4 zero = {};
    #pragma unroll
    for (int nt = 0; nt < 4; ++nt) acc[nt] = zero;
    #pragma unroll
    for (int ks = 0; ks < 4; ++ks) {
        const int kb = ks * 32 + q * 8;
        bf16x8 aH = *(const bf16x8*)(&hh[g * 16 + m16][kb]);
        bf16x8 aL = *(const bf16x8*)(&hl[g * 16 + m16][kb]);
        #pragma unroll
        for (int nt = 0; nt < 4; ++nt) {
            const size_t wo = (size_t)(c * 64 + nt * 16 + m16) * F + kb;
            bf16x8 bh = *(const bf16x8*)(w2h + wo);
            bf16x8 bl = *(const bf16x8*)(w2l + wo);
            acc[nt] = __builtin_amdgcn_mfma_f32_16x16x32_bf16(aH, bh, acc[nt], 0, 0, 0);
            acc[nt] = __builtin_amdgcn_mfma_f32_16x16x32_bf16(aL, bh, acc[nt], 0, 0, 0);
            acc[nt] = __builtin_amdgcn_mfma_f32_16x16x32_bf16(aH, bl, acc[nt], 0, 0, 0);
        }
    }
    const int rowD0 = blockIdx.x * 32 + g * 16 + q * 4;
    #pragma unroll
    for (int nt = 0; nt < 4; ++nt) {
        const int col = c * 64 + nt * 16 + m16;
        #pragma unroll
        for (int r = 0; r < 4; ++r) {
            const int row = rowD0 + r;
            if (row < M) out[(size_t)row * F + col] = acc[nt][r];
        }
    }
}

// ---------------------------------------------------------------------------
extern "C" void kernel_launch(void* const* d_in, const int* in_sizes, int n_in,
                              void* d_out, int out_size, void* d_ws, size_t ws_size,
                              hipStream_t stream)
{
    const float* x         = (const float*)d_in[0];
    const float* edge_attr = (const float*)d_in[1];
    const int*   eidx      = (const int*)d_in[2];
    const float* fc1w      = (const float*)d_in[3];
    const float* fw1       = (const float*)d_in[4];
    const float* fb1       = (const float*)d_in[5];
    const float* fw2       = (const float*)d_in[6];
    const float* fb2       = (const float*)d_in[7];
    const float* sw1       = (const float*)d_in[8];
    const float* sw2       = (const float*)d_in[9];
    float* out = (float*)d_out;

    const int N = in_sizes[0] / F;     // 50000
    const int E = in_sizes[1] / F;     // 600000

    float* agg = (float*)d_ws;
    float* y   = agg + (size_t)N * F;
    __bf16* wb = (__bf16*)(y + (size_t)N * F);
    const int WSZ = F * F;
    __bf16* fc1h = wb;            __bf16* fc1l = wb + WSZ;
    __bf16* fw1h = wb + 2 * WSZ;  __bf16* fw2h = wb + 3 * WSZ;
    __bf16* sw1h = wb + 4 * WSZ;  __bf16* sw1l = wb + 5 * WSZ;
    __bf16* sw2h = wb + 6 * WSZ;  __bf16* sw2l = wb + 7 * WSZ;
    _Float16* Ws = (_Float16*)(wb + 8 * WSZ);    // E*F fp16, 256B-aligned rows
    int* cnt   = (int*)(Ws + (size_t)E * F);     // N: hist -> row_ptr end offsets
    int* bsums = cnt + N;                        // 64 scan block sums
    int* pos   = bsums + 64;                     // E: slot of original edge e
    int* ssrc  = pos + E;                        // E: src per sorted slot
    int* sdst  = ssrc + E;                       // E: dst per sorted slot

    const int nb1 = (N + 1023) / 1024;

    // agg must start at zero (atomic accumulation target)
    hipMemsetAsync(agg, 0, (size_t)N * F * sizeof(float), stream);

    prep_kernel<<<(WSZ + 255) / 256, 256, 0, stream>>>(
        fc1w, fw1, fw2, sw1, sw2, fc1h, fc1l, fw1h, fw2h, sw1h, sw1l, sw2h, sw2l,
        cnt, N);

    fc1_kernel<<<(N + 31) / 32, 256, 0, stream>>>(x, fc1h, fc1l, y, N);

    // build dst-sorted edge order
    hist_kernel<<<(E + 255) / 256, 256, 0, stream>>>(eidx, cnt, E);
    scan1_kernel<<<nb1, 1024, 0, stream>>>(cnt, bsums, N);
    scan2_kernel<<<1, 64, 0, stream>>>(bsums, nb1);
    scan3_kernel<<<nb1, 1024, 0, stream>>>(cnt, bsums, N);
    scatter_kernel<<<(E + 255) / 256, 256, 0, stream>>>(eidx, cnt, pos, ssrc, sdst, E);

    // E1: streaming filter MLP, fp16 W scattered to sorted slots
    filter_kernel<<<(E + 63) / 64, 256, 0, stream>>>(
        edge_attr, pos, fb1, fb2, fw1h, fw2h, Ws, E);

    // E2: sequential gather-reduce with run-merged atomics
    agg_kernel<<<(E + 63) / 64, 256, 0, stream>>>(y, Ws, ssrc, sdst, agg, E);

    state_kernel<<<(N + 31) / 32, 256, 0, stream>>>(
        agg, sw1h, sw1l, sw2h, sw2l, out, N);
}

// Round 4
// 849.180 us; speedup vs baseline: 1.1989x; 1.1381x over previous
//
#include <hip/hip_runtime.h>

#define F 128            // feature dim (HID == NF == 128)
#define SP 16            // sorted slots per wave in agg_kernel

typedef __attribute__((ext_vector_type(8))) __bf16 bf16x8;
typedef __attribute__((ext_vector_type(4))) float floatx4;
typedef __attribute__((ext_vector_type(2))) _Float16 f16x2;

// shifted softplus: softplus(x) - log(2) == log((1+e^x)/2)
__device__ __forceinline__ float ssp(float x) {
    return __logf(fmaf(0.5f, __expf(x), 0.5f));
}

__device__ __forceinline__ floatx4 mfma_bf16(bf16x8 a, bf16x8 b, floatx4 c) {
    return __builtin_amdgcn_mfma_f32_16x16x32_bf16(a, b, c, 0, 0, 0);
}

// ---------------------------------------------------------------------------
// prep: weights f32 -> bf16(hi)+bf16(lo); also zero the histogram counters
// ---------------------------------------------------------------------------
__global__ void prep_kernel(const float* __restrict__ fc1w,
                            const float* __restrict__ fw1,
                            const float* __restrict__ fw2,
                            const float* __restrict__ sw1,
                            const float* __restrict__ sw2,
                            __bf16* __restrict__ fc1h, __bf16* __restrict__ fc1l,
                            __bf16* __restrict__ fw1h, __bf16* __restrict__ fw2h,
                            __bf16* __restrict__ sw1h, __bf16* __restrict__ sw1l,
                            __bf16* __restrict__ sw2h, __bf16* __restrict__ sw2l,
                            int* __restrict__ cnt, int N)
{
    int i = blockIdx.x * blockDim.x + threadIdx.x;
    for (int j = i; j < N; j += gridDim.x * blockDim.x) cnt[j] = 0;
    if (i >= F * F) return;
    float v; __bf16 h;
    v = fc1w[i]; h = (__bf16)v; fc1h[i] = h; fc1l[i] = (__bf16)(v - (float)h);
    v = sw1[i];  h = (__bf16)v; sw1h[i] = h; sw1l[i] = (__bf16)(v - (float)h);
    v = sw2[i];  h = (__bf16)v; sw2h[i] = h; sw2l[i] = (__bf16)(v - (float)h);
    fw1h[i] = (__bf16)fw1[i];
    fw2h[i] = (__bf16)fw2[i];
}

// ---------------------------------------------------------------------------
// CSR build: histogram of dst -> exclusive scan -> cursor scatter.
// pos[e] = sorted slot of original edge e (inverse permutation).
// ---------------------------------------------------------------------------
__global__ __launch_bounds__(256) void hist_kernel(const int* __restrict__ eidx,
                                                   int* __restrict__ cnt, int E)
{
    int i = blockIdx.x * 256 + threadIdx.x;
    if (i < E) atomicAdd(&cnt[eidx[E + i]], 1);
}

__global__ __launch_bounds__(1024) void scan1_kernel(int* __restrict__ cnt,
                                                     int* __restrict__ bsums, int N)
{
    __shared__ int sd[1024];
    const int t = threadIdx.x;
    const int i = blockIdx.x * 1024 + t;
    int v = (i < N) ? cnt[i] : 0;
    sd[t] = v;
    __syncthreads();
    for (int off = 1; off < 1024; off <<= 1) {
        int add = (t >= off) ? sd[t - off] : 0;
        __syncthreads();
        sd[t] += add;
        __syncthreads();
    }
    if (i < N) cnt[i] = sd[t] - v;          // exclusive
    if (t == 1023) bsums[blockIdx.x] = sd[t];
}

__global__ void scan2_kernel(int* __restrict__ bsums, int nb)
{
    const int lane = threadIdx.x & 63;
    int v = (lane < nb) ? bsums[lane] : 0;
    int acc = v;
    #pragma unroll
    for (int off = 1; off < 64; off <<= 1) {
        int t = __shfl_up(acc, off);
        if (lane >= off) acc += t;
    }
    if (lane < nb) bsums[lane] = acc - v;   // exclusive
}

__global__ __launch_bounds__(1024) void scan3_kernel(int* __restrict__ cnt,
                                                     const int* __restrict__ bsums, int N)
{
    int i = blockIdx.x * 1024 + threadIdx.x;
    if (i < N) cnt[i] += bsums[blockIdx.x];
}

__global__ __launch_bounds__(256) void scatter_kernel(const int* __restrict__ eidx,
                                                      int* __restrict__ cursor,
                                                      int* __restrict__ pos,
                                                      int* __restrict__ ssrc,
                                                      int* __restrict__ sdst, int E)
{
    int i = blockIdx.x * 256 + threadIdx.x;
    if (i < E) {
        int d = eidx[E + i];
        int slot = atomicAdd(&cursor[d], 1);
        pos[i] = slot;
        ssrc[slot] = eidx[i];
        sdst[slot] = d;
    }
}

// ---------------------------------------------------------------------------
// y = x @ fc1_w.T   (split bf16, 3-term MFMA -> ~f32 exact)
// 64 rows/block, wave owns 16 rows x 128 cols; batched B-fragment loads.
// No LDS, no barriers.
// ---------------------------------------------------------------------------
__global__ __launch_bounds__(256, 3) void fc1_kernel(
    const float* __restrict__ x, const __bf16* __restrict__ wh,
    const __bf16* __restrict__ wl, float* __restrict__ y, int M)
{
    const int tid = threadIdx.x;
    const int wv = tid >> 6, lane = tid & 63;
    const int m16 = lane & 15, q = lane >> 4;
    const int r0 = blockIdx.x * 64 + wv * 16;
    const int rowA0 = r0 + m16;
    const int rowA = rowA0 < M ? rowA0 : M - 1;

    floatx4 acc[8] = {};
    #pragma unroll
    for (int ks = 0; ks < 4; ++ks) {
        const int kb = ks * 32 + q * 8;
        const float4* p = (const float4*)(x + (size_t)rowA * F + kb);
        float4 a0 = p[0], a1 = p[1];
        float fv[8] = {a0.x, a0.y, a0.z, a0.w, a1.x, a1.y, a1.z, a1.w};
        bf16x8 ah, al;
        #pragma unroll
        for (int i = 0; i < 8; ++i) {
            __bf16 h = (__bf16)fv[i];
            ah[i] = h; al[i] = (__bf16)(fv[i] - (float)h);
        }
        bf16x8 bH[8], bL[8];
        #pragma unroll
        for (int nt = 0; nt < 8; ++nt) {
            const size_t wo = (size_t)(nt * 16 + m16) * F + kb;
            bH[nt] = *(const bf16x8*)(wh + wo);
            bL[nt] = *(const bf16x8*)(wl + wo);
        }
        #pragma unroll
        for (int nt = 0; nt < 8; ++nt) {
            acc[nt] = mfma_bf16(ah, bH[nt], acc[nt]);
            acc[nt] = mfma_bf16(al, bH[nt], acc[nt]);
            acc[nt] = mfma_bf16(ah, bL[nt], acc[nt]);
        }
    }
    #pragma unroll
    for (int nt = 0; nt < 8; ++nt) {
        const int col = nt * 16 + m16;
        #pragma unroll
        for (int r = 0; r < 4; ++r) {
            const int row = r0 + q * 4 + r;
            if (row < M) y[(size_t)row * F + col] = acc[nt][r];
        }
    }
}

// ---------------------------------------------------------------------------
// Pass E1: W = ssp(ssp(ea@f_w1.T+b1)@f_w2.T+b2) in ORIGINAL edge order,
// stored fp16 at dst-sorted slot pos[e].
// 128 edges/block, wave owns 32 rows x 128 cols (2 row-tiles, shared B-frags).
// LDS staging is wave-local but guarded by cheap block barriers (compiler
// may not preserve cross-lane LDS write->read order without them).
// ---------------------------------------------------------------------------
__global__ __launch_bounds__(256, 3) void filter_kernel(
    const float* __restrict__ edge_attr,
    const int* __restrict__ pos,
    const float* __restrict__ fb1, const float* __restrict__ fb2,
    const __bf16* __restrict__ fw1, const __bf16* __restrict__ fw2,
    _Float16* __restrict__ Ws, int E)
{
    __shared__ __align__(16) unsigned short smem[4][32][136]; // bf16 h1 -> fp16 wo
    __shared__ int pos_s[4][32];

    const int tid = threadIdx.x;
    const int wv = tid >> 6, lane = tid & 63;
    const int m16 = lane & 15, q = lane >> 4;
    const int e0 = blockIdx.x * 128 + wv * 32;

    __bf16 (*h1)[136] = (__bf16 (*)[136])smem[wv];
    _Float16 (*wo)[136] = (_Float16 (*)[136])smem[wv];

    if (lane < 32) { int e = e0 + lane; pos_s[wv][lane] = pos[e < E ? e : E - 1]; }

    const int rA0 = e0 + m16;
    const int rA1 = e0 + 16 + m16;
    const int r0c = rA0 < E ? rA0 : E - 1;
    const int r1c = rA1 < E ? rA1 : E - 1;

    // ---- stage 1: h1 = ssp(ea @ f_w1.T + b1) ----
    floatx4 acc0[8] = {}, acc1[8] = {};
    #pragma unroll
    for (int ks = 0; ks < 4; ++ks) {
        const int kb = ks * 32 + q * 8;
        const float4* p0 = (const float4*)(edge_attr + (size_t)r0c * F + kb);
        const float4* p1 = (const float4*)(edge_attr + (size_t)r1c * F + kb);
        float4 a00 = p0[0], a01 = p0[1];
        float4 a10 = p1[0], a11 = p1[1];
        float f0[8] = {a00.x, a00.y, a00.z, a00.w, a01.x, a01.y, a01.z, a01.w};
        float f1[8] = {a10.x, a10.y, a10.z, a10.w, a11.x, a11.y, a11.z, a11.w};
        bf16x8 aF0, aF1;
        #pragma unroll
        for (int i = 0; i < 8; ++i) { aF0[i] = (__bf16)f0[i]; aF1[i] = (__bf16)f1[i]; }
        bf16x8 bF[8];
        #pragma unroll
        for (int nt = 0; nt < 8; ++nt)
            bF[nt] = *(const bf16x8*)(fw1 + (size_t)(nt * 16 + m16) * F + kb);
        #pragma unroll
        for (int nt = 0; nt < 8; ++nt) {
            acc0[nt] = mfma_bf16(aF0, bF[nt], acc0[nt]);
            acc1[nt] = mfma_bf16(aF1, bF[nt], acc1[nt]);
        }
    }
    #pragma unroll
    for (int nt = 0; nt < 8; ++nt) {
        const int col = nt * 16 + m16;
        const float b = fb1[col];
        #pragma unroll
        for (int r = 0; r < 4; ++r) {
            h1[q * 4 + r][col]      = (__bf16)ssp(acc0[nt][r] + b);
            h1[16 + q * 4 + r][col] = (__bf16)ssp(acc1[nt][r] + b);
        }
    }
    __syncthreads();

    // ---- stage 2: W = ssp(h1 @ f_w2.T + b2) ----
    floatx4 zero = {};
    #pragma unroll
    for (int nt = 0; nt < 8; ++nt) { acc0[nt] = zero; acc1[nt] = zero; }
    #pragma unroll
    for (int ks = 0; ks < 4; ++ks) {
        const int kb = ks * 32 + q * 8;
        bf16x8 aF0 = *(const bf16x8*)(&h1[m16][kb]);
        bf16x8 aF1 = *(const bf16x8*)(&h1[16 + m16][kb]);
        bf16x8 bF[8];
        #pragma unroll
        for (int nt = 0; nt < 8; ++nt)
            bF[nt] = *(const bf16x8*)(fw2 + (size_t)(nt * 16 + m16) * F + kb);
        #pragma unroll
        for (int nt = 0; nt < 8; ++nt) {
            acc0[nt] = mfma_bf16(aF0, bF[nt], acc0[nt]);
            acc1[nt] = mfma_bf16(aF1, bF[nt], acc1[nt]);
        }
    }
    __syncthreads();   // all h1 reads done before smem is retyped to fp16 wo

    #pragma unroll
    for (int nt = 0; nt < 8; ++nt) {
        const int col = nt * 16 + m16;
        const float b = fb2[col];
        #pragma unroll
        for (int r = 0; r < 4; ++r) {
            wo[q * 4 + r][col]      = (_Float16)ssp(acc0[nt][r] + b);
            wo[16 + q * 4 + r][col] = (_Float16)ssp(acc1[nt][r] + b);
        }
    }
    __syncthreads();

    // coalesced scatter: 256B contiguous per row at slot pos_s
    #pragma unroll
    for (int it = 0; it < 8; ++it) {
        const int row = it * 4 + q;
        const int e = e0 + row;
        if (e < E) {
            const uint4 v = *(const uint4*)(&wo[row][m16 * 8]);
            *(uint4*)(Ws + (size_t)pos_s[wv][row] * F + m16 * 8) = v;
        }
    }
}

// ---------------------------------------------------------------------------
// Pass E2: agg[dst] += y[src] * W  over dst-SORTED slots (run-merged atomics)
// ---------------------------------------------------------------------------
__global__ __launch_bounds__(256) void agg_kernel(
    const float* __restrict__ y, const _Float16* __restrict__ Ws,
    const int* __restrict__ ssrc, const int* __restrict__ sdst,
    float* __restrict__ agg, int E)
{
    const int tid = threadIdx.x;
    const int wv = tid >> 6, lane = tid & 63;
    const long s0 = ((long)blockIdx.x * 4 + wv) * SP;
    if (s0 >= E) return;

    int msrc = 0, mdst = -1;
    if (lane < SP) {
        long s = s0 + lane;
        if (s < E) { msrc = ssrc[s]; mdst = sdst[s]; }
    }
    const int col = lane * 2;
    float rx = 0.f, ry = 0.f;
    int rdst = -1;

    #pragma unroll
    for (int c = 0; c < SP / 4; ++c) {
        float2 yv[4]; float wx[4], wy[4]; int pdst[4]; bool okr[4];
        #pragma unroll
        for (int r = 0; r < 4; ++r) {
            const int p = c * 4 + r;
            const long s = s0 + p;
            okr[r] = (s < E);
            const int sp = __shfl(msrc, p);
            pdst[r] = __shfl(mdst, p);
            const long sc = okr[r] ? s : (long)(E - 1);
            const int spc = okr[r] ? sp : 0;
            yv[r] = *(const float2*)(y + (size_t)spc * F + col);
            f16x2 w2 = *(const f16x2*)(Ws + (size_t)sc * F + col);
            wx[r] = (float)w2[0]; wy[r] = (float)w2[1];
        }
        #pragma unroll
        for (int r = 0; r < 4; ++r) {
            if (!okr[r]) continue;
            if (pdst[r] != rdst) {
                if (rdst >= 0) {
                    unsafeAtomicAdd(&agg[(size_t)rdst * F + col], rx);
                    unsafeAtomicAdd(&agg[(size_t)rdst * F + col + 1], ry);
                }
                rx = 0.f; ry = 0.f; rdst = pdst[r];
            }
            rx = fmaf(yv[r].x, wx[r], rx);
            ry = fmaf(yv[r].y, wy[r], ry);
        }
    }
    if (rdst >= 0) {
        unsafeAtomicAdd(&agg[(size_t)rdst * F + col], rx);
        unsafeAtomicAdd(&agg[(size_t)rdst * F + col + 1], ry);
    }
}

// ---------------------------------------------------------------------------
// out = ssp(agg @ s_w1.T) @ s_w2.T   (split bf16 both stages -> ~f32 exact)
// 64 rows/block, wave owns 16 rows x 128 cols; wave-local hh/hl + barrier.
// ---------------------------------------------------------------------------
__global__ __launch_bounds__(256, 3) void state_kernel(
    const float* __restrict__ agg,
    const __bf16* __restrict__ w1h, const __bf16* __restrict__ w1l,
    const __bf16* __restrict__ w2h, const __bf16* __restrict__ w2l,
    float* __restrict__ out, int M)
{
    __shared__ __align__(16) __bf16 hhs[4][16][136];
    __shared__ __align__(16) __bf16 hls[4][16][136];

    const int tid = threadIdx.x;
    const int wv = tid >> 6, lane = tid & 63;
    const int m16 = lane & 15, q = lane >> 4;
    const int r0 = blockIdx.x * 64 + wv * 16;
    const int rowA0 = r0 + m16;
    const int rowA = rowA0 < M ? rowA0 : M - 1;

    __bf16 (*hh)[136] = hhs[wv];
    __bf16 (*hl)[136] = hls[wv];

    // stage 1: h = ssp(agg @ s_w1.T)
    floatx4 acc[8] = {};
    #pragma unroll
    for (int ks = 0; ks < 4; ++ks) {
        const int kb = ks * 32 + q * 8;
        const float4* p = (const float4*)(agg + (size_t)rowA * F + kb);
        float4 a0 = p[0], a1 = p[1];
        float fv[8] = {a0.x, a0.y, a0.z, a0.w, a1.x, a1.y, a1.z, a1.w};
        bf16x8 ah, al;
        #pragma unroll
        for (int i = 0; i < 8; ++i) {
            __bf16 h = (__bf16)fv[i];
            ah[i] = h; al[i] = (__bf16)(fv[i] - (float)h);
        }
        bf16x8 bH[8], bL[8];
        #pragma unroll
        for (int nt = 0; nt < 8; ++nt) {
            const size_t wo = (size_t)(nt * 16 + m16) * F + kb;
            bH[nt] = *(const bf16x8*)(w1h + wo);
            bL[nt] = *(const bf16x8*)(w1l + wo);
        }
        #pragma unroll
        for (int nt = 0; nt < 8; ++nt) {
            acc[nt] = mfma_bf16(ah, bH[nt], acc[nt]);
            acc[nt] = mfma_bf16(al, bH[nt], acc[nt]);
            acc[nt] = mfma_bf16(ah, bL[nt], acc[nt]);
        }
    }
    #pragma unroll
    for (int nt = 0; nt < 8; ++nt) {
        const int col = nt * 16 + m16;
        #pragma unroll
        for (int r = 0; r < 4; ++r) {
            const int row = q * 4 + r;
            const float h = ssp(acc[nt][r]);
            const __bf16 H = (__bf16)h;
            hh[row][col] = H;
            hl[row][col] = (__bf16)(h - (float)H);
        }
    }
    __syncthreads();

    // stage 2: out = h @ s_w2.T
    floatx4 zero = {};
    #pragma unroll
    for (int nt = 0; nt < 8; ++nt) acc[nt] = zero;
    #pragma unroll
    for (int ks = 0; ks < 4; ++ks) {
        const int kb = ks * 32 + q * 8;
        bf16x8 aH = *(const bf16x8*)(&hh[m16][kb]);
        bf16x8 aL = *(const bf16x8*)(&hl[m16][kb]);
        bf16x8 bH[8], bL[8];
        #pragma unroll
        for (int nt = 0; nt < 8; ++nt) {
            const size_t wo = (size_t)(nt * 16 + m16) * F + kb;
            bH[nt] = *(const bf16x8*)(w2h + wo);
            bL[nt] = *(const bf16x8*)(w2l + wo);
        }
        #pragma unroll
        for (int nt = 0; nt < 8; ++nt) {
            acc[nt] = mfma_bf16(aH, bH[nt], acc[nt]);
            acc[nt] = mfma_bf16(aL, bH[nt], acc[nt]);
            acc[nt] = mfma_bf16(aH, bL[nt], acc[nt]);
        }
    }
    #pragma unroll
    for (int nt = 0; nt < 8; ++nt) {
        const int col = nt * 16 + m16;
        #pragma unroll
        for (int r = 0; r < 4; ++r) {
            const int row = r0 + q * 4 + r;
            if (row < M) out[(size_t)row * F + col] = acc[nt][r];
        }
    }
}

// ---------------------------------------------------------------------------
extern "C" void kernel_launch(void* const* d_in, const int* in_sizes, int n_in,
                              void* d_out, int out_size, void* d_ws, size_t ws_size,
                              hipStream_t stream)
{
    const float* x         = (const float*)d_in[0];
    const float* edge_attr = (const float*)d_in[1];
    const int*   eidx      = (const int*)d_in[2];
    const float* fc1w      = (const float*)d_in[3];
    const float* fw1       = (const float*)d_in[4];
    const float* fb1       = (const float*)d_in[5];
    const float* fw2       = (const float*)d_in[6];
    const float* fb2       = (const float*)d_in[7];
    const float* sw1       = (const float*)d_in[8];
    const float* sw2       = (const float*)d_in[9];
    float* out = (float*)d_out;

    const int N = in_sizes[0] / F;     // 50000
    const int E = in_sizes[1] / F;     // 600000

    float* agg = (float*)d_ws;
    float* y   = agg + (size_t)N * F;
    __bf16* wb = (__bf16*)(y + (size_t)N * F);
    const int WSZ = F * F;
    __bf16* fc1h = wb;            __bf16* fc1l = wb + WSZ;
    __bf16* fw1h = wb + 2 * WSZ;  __bf16* fw2h = wb + 3 * WSZ;
    __bf16* sw1h = wb + 4 * WSZ;  __bf16* sw1l = wb + 5 * WSZ;
    __bf16* sw2h = wb + 6 * WSZ;  __bf16* sw2l = wb + 7 * WSZ;
    _Float16* Ws = (_Float16*)(wb + 8 * WSZ);    // E*F fp16, 256B-aligned rows
    int* cnt   = (int*)(Ws + (size_t)E * F);     // N: hist -> cursor
    int* bsums = cnt + N;                        // 64 scan block sums
    int* pos   = bsums + 64;                     // E: slot of original edge e
    int* ssrc  = pos + E;                        // E: src per sorted slot
    int* sdst  = ssrc + E;                       // E: dst per sorted slot

    const int nb1 = (N + 1023) / 1024;

    hipMemsetAsync(agg, 0, (size_t)N * F * sizeof(float), stream);

    prep_kernel<<<(WSZ + 255) / 256, 256, 0, stream>>>(
        fc1w, fw1, fw2, sw1, sw2, fc1h, fc1l, fw1h, fw2h, sw1h, sw1l, sw2h, sw2l,
        cnt, N);

    fc1_kernel<<<(N + 63) / 64, 256, 0, stream>>>(x, fc1h, fc1l, y, N);

    // build dst-sorted edge order
    hist_kernel<<<(E + 255) / 256, 256, 0, stream>>>(eidx, cnt, E);
    scan1_kernel<<<nb1, 1024, 0, stream>>>(cnt, bsums, N);
    scan2_kernel<<<1, 64, 0, stream>>>(bsums, nb1);
    scan3_kernel<<<nb1, 1024, 0, stream>>>(cnt, bsums, N);
    scatter_kernel<<<(E + 255) / 256, 256, 0, stream>>>(eidx, cnt, pos, ssrc, sdst, E);

    // E1: streaming filter MLP, fp16 W scattered to sorted slots
    filter_kernel<<<(E + 127) / 128, 256, 0, stream>>>(
        edge_attr, pos, fb1, fb2, fw1h, fw2h, Ws, E);

    // E2: sequential gather-reduce with run-merged atomics
    agg_kernel<<<(E + 63) / 64, 256, 0, stream>>>(y, Ws, ssrc, sdst, agg, E);

    state_kernel<<<(N + 63) / 64, 256, 0, stream>>>(
        agg, sw1h, sw1l, sw2h, sw2l, out, N);
}